// Round 5
// baseline (844.125 us; speedup 1.0000x reference)
//
#include <hip/hip_runtime.h>

// Sizes: N=500000, C=128, H=256, A=10, E=600000, B=50000.
// R5: gemm with coalesced LDS staging (bf16, pad-8) + fused action-weighted
// state residual (sstate); readout no longer reads state (xws fits L3).

typedef __bf16 bf16x8 __attribute__((ext_vector_type(8)));
typedef float f32x4 __attribute__((ext_vector_type(4)));

// ---- per-edge: degree count + adjacency linked list -------------------------
__global__ __launch_bounds__(256) void k_edges(const int* __restrict__ dst, int E,
                                               int* __restrict__ deg,
                                               int* __restrict__ head,
                                               int* __restrict__ nxt) {
    int e = blockIdx.x * 256 + threadIdx.x;
    if (e < E) {
        int d = dst[e];
        atomicAdd(&deg[d], 1);
        nxt[e] = atomicExch(&head[d], e);
    }
}

// ---- dinv = rsqrt(deg + 1)  (+1 = self loop) --------------------------------
__global__ __launch_bounds__(256) void k_dinv(const int* __restrict__ deg,
                                              float* __restrict__ dinv, int N) {
    int i = blockIdx.x * 256 + threadIdx.x;
    if (i < N) dinv[i] = rsqrtf((float)deg[i] + 1.0f);
}

// ---- transpose-convert weights: Wt[n*K+k] = bf16(W[k*Nc+n]) -----------------
__global__ __launch_bounds__(256) void k_tconv(const float* __restrict__ W,
                                               __bf16* __restrict__ Wt,
                                               int kbits, int total, int Nc) {
    int i = blockIdx.x * 256 + threadIdx.x;
    if (i < total) {
        int n = i >> kbits;
        int k = i & ((1 << kbits) - 1);
        Wt[i] = (__bf16)W[(long)k * Nc + n];
    }
}

// ---- gemm + residual: xws = bf16(dinv.*(state@W_gcn)),
//      sstate[g] += sum_rows aw*state  (fp32, via LDS then global atomics) ----
__global__ __launch_bounds__(256) void k_gemm(const float* __restrict__ X,
                                              const __bf16* __restrict__ Wt,
                                              const float* __restrict__ dinv,
                                              const float* __restrict__ action,
                                              __bf16* __restrict__ Y,
                                              float* __restrict__ sstate,
                                              int N, int B) {
    __shared__ __bf16 xt[64 * 136];   // 64 rows, stride 136 (pad 8) = 17 KB
    __shared__ float ss[8 * 128];     // per-block group partials, 4 KB
    int tid = threadIdx.x;
    long row0 = (long)blockIdx.x * 64;
    int g0 = (int)(row0 / 10);
    for (int i = tid; i < 1024; i += 256) ss[i] = 0.f;
    __syncthreads();
    // stage 64x128 fp32 -> bf16 LDS, coalesced 32 B/lane, + residual partials
    #pragma unroll
    for (int it = 0; it < 4; it++) {
        int r = it * 16 + (tid >> 4);
        long row = row0 + r;
        if (row < N) {
            int c0 = (tid & 15) * 8;
            const float* p = X + row * 128 + c0;
            float4 v0 = *(const float4*)p;
            float4 v1 = *(const float4*)(p + 4);
            float v[8] = {v0.x, v0.y, v0.z, v0.w, v1.x, v1.y, v1.z, v1.w};
            bf16x8 bv;
            #pragma unroll
            for (int k = 0; k < 8; k++) bv[k] = (__bf16)v[k];
            *(bf16x8*)(xt + r * 136 + c0) = bv;
            float aw = action[row] * 10.f;
            int g = (int)(row / 10) - g0;
            float* sp = ss + g * 128 + c0;
            #pragma unroll
            for (int k = 0; k < 8; k++) atomicAdd(&sp[k], aw * v[k]);
        }
    }
    __syncthreads();
    int wave = tid >> 6, lane = tid & 63;
    int m = lane & 15, quad = lane >> 4;
    long wrow0 = row0 + wave * 16;
    if (wrow0 < N) {   // N%16==0, so a valid wave tile is fully valid
        f32x4 acc[8] = {};
        #pragma unroll
        for (int kt = 0; kt < 4; kt++) {
            int k0 = kt * 32 + quad * 8;
            bf16x8 a = *(const bf16x8*)(xt + (wave * 16 + m) * 136 + k0);
            #pragma unroll
            for (int t = 0; t < 8; t++) {
                bf16x8 b = *(const bf16x8*)(Wt + (t * 16 + m) * 128 + k0);
                acc[t] = __builtin_amdgcn_mfma_f32_16x16x32_bf16(a, b, acc[t],
                                                                  0, 0, 0);
            }
        }
        float dv[4];
        #pragma unroll
        for (int r = 0; r < 4; r++) dv[r] = dinv[wrow0 + quad * 4 + r];
        #pragma unroll
        for (int t = 0; t < 8; t++)
            #pragma unroll
            for (int r = 0; r < 4; r++)
                Y[(wrow0 + quad * 4 + r) * 128 + t * 16 + m] =
                    (__bf16)(acc[t][r] * dv[r]);
    }
    __syncthreads();
    // flush group partials (groups may straddle blocks -> global atomics)
    for (int i = tid; i < 1024; i += 256) {
        long gg = g0 + (i >> 7);
        if (gg < B) {
            float vsum = ss[i];
            if (vsum != 0.f) atomicAdd(&sstate[gg * 128 + (i & 127)], vsum);
        }
    }
}

// ---- fused aggregate + relu + readout (residual via sstate) -----------------
// One block per b. 128 thr = 8 node slots x 16 lanes; lane owns 8 channels.
__global__ __launch_bounds__(128) void k_readout(const int* __restrict__ head,
                                                 const int* __restrict__ nxt,
                                                 const int* __restrict__ e_src,
                                                 const float* __restrict__ dinv,
                                                 const __bf16* __restrict__ xws,
                                                 const float* __restrict__ sstate,
                                                 const float* __restrict__ bgcn,
                                                 const float* __restrict__ action,
                                                 __bf16* __restrict__ xB, int B) {
    __shared__ float red[16][8];
    int b = blockIdx.x;
    int tid = threadIdx.x;
    int lane16 = tid & 15;
    int slot = tid >> 4;       // 0..7
    int c0 = lane16 * 8;
    float4 bg0 = *(const float4*)(bgcn + c0);
    float4 bg1 = *(const float4*)(bgcn + c0 + 4);
    float bg[8] = {bg0.x, bg0.y, bg0.z, bg0.w, bg1.x, bg1.y, bg1.z, bg1.w};
    float acc[8] = {};
    for (int a = slot; a < 10; a += 8) {
        int n = b * 10 + a;
        float s[8];
        bf16x8 x = *(const bf16x8*)(xws + (size_t)n * 128 + c0);
        #pragma unroll
        for (int k = 0; k < 8; k++) s[k] = (float)x[k];
        for (int j = head[n]; j >= 0; j = nxt[j]) {
            int sr = e_src[j];
            bf16x8 g = *(const bf16x8*)(xws + (size_t)sr * 128 + c0);
            #pragma unroll
            for (int k = 0; k < 8; k++) s[k] += (float)g[k];
        }
        float di = dinv[n];
        float aw = action[n] * 10.f;
        #pragma unroll
        for (int k = 0; k < 8; k++)
            acc[k] += aw * fmaxf(di * s[k] + bg[k], 0.f);
    }
    #pragma unroll
    for (int k = 0; k < 8; k++) {
        acc[k] += __shfl_down(acc[k], 32);
        acc[k] += __shfl_down(acc[k], 16);
    }
    if (tid >= 64 && tid < 80) {
        #pragma unroll
        for (int k = 0; k < 8; k++) red[tid - 64][k] = acc[k];
    }
    __syncthreads();
    if (tid < 16) {
        float4 s0 = *(const float4*)(sstate + (size_t)b * 128 + c0);
        float4 s1 = *(const float4*)(sstate + (size_t)b * 128 + c0 + 4);
        float sv[8] = {s0.x, s0.y, s0.z, s0.w, s1.x, s1.y, s1.z, s1.w};
        bf16x8 o;
        #pragma unroll
        for (int k = 0; k < 8; k++)
            o[k] = (__bf16)(acc[k] + red[tid][k] + sv[k]);
        *(bf16x8*)(xB + (size_t)b * 128 + c0) = o;
    }
}

// ---- MLP head via MFMA: relu(x@W1+b1) -> relu(@W2+b2) -> @W3+b3 -------------
__global__ __launch_bounds__(256) void k_mlp(const __bf16* __restrict__ xB,
                                             const __bf16* __restrict__ W1t,
                                             const float* __restrict__ b1,
                                             const __bf16* __restrict__ W2t,
                                             const float* __restrict__ b2,
                                             const float* __restrict__ W3,
                                             const float* __restrict__ b3,
                                             float* __restrict__ out, int B) {
    __shared__ __bf16 hs[16][264];
    __shared__ float osum[4][16];
    int wave = threadIdx.x >> 6;
    int lane = threadIdx.x & 63;
    int m = lane & 15;
    int quad = lane >> 4;
    long r0 = (long)blockIdx.x * 16;

    f32x4 acc[4] = {};
    #pragma unroll
    for (int kt = 0; kt < 4; kt++) {
        int k0 = kt * 32 + quad * 8;
        bf16x8 a = *(const bf16x8*)(xB + (r0 + m) * 128 + k0);
        #pragma unroll
        for (int t = 0; t < 4; t++) {
            int n = wave * 64 + t * 16 + m;
            bf16x8 b = *(const bf16x8*)(W1t + (long)n * 128 + k0);
            acc[t] = __builtin_amdgcn_mfma_f32_16x16x32_bf16(a, b, acc[t], 0, 0, 0);
        }
    }
    #pragma unroll
    for (int t = 0; t < 4; t++) {
        int n = wave * 64 + t * 16 + m;
        float bb = b1[n];
        #pragma unroll
        for (int r = 0; r < 4; r++)
            hs[quad * 4 + r][n] = (__bf16)fmaxf(acc[t][r] + bb, 0.f);
    }
    __syncthreads();

    f32x4 acc2[4] = {};
    #pragma unroll
    for (int kt = 0; kt < 8; kt++) {
        int k0 = kt * 32 + quad * 8;
        bf16x8 a = *(const bf16x8*)(&hs[m][k0]);
        #pragma unroll
        for (int t = 0; t < 4; t++) {
            int n = wave * 64 + t * 16 + m;
            bf16x8 b = *(const bf16x8*)(W2t + (long)n * 256 + k0);
            acc2[t] = __builtin_amdgcn_mfma_f32_16x16x32_bf16(a, b, acc2[t], 0, 0, 0);
        }
    }

    float part[4] = {0.f, 0.f, 0.f, 0.f};
    #pragma unroll
    for (int t = 0; t < 4; t++) {
        int n = wave * 64 + t * 16 + m;
        float bb = b2[n], w3 = W3[n];
        #pragma unroll
        for (int r = 0; r < 4; r++)
            part[r] += fmaxf(acc2[t][r] + bb, 0.f) * w3;
    }
    #pragma unroll
    for (int off = 8; off; off >>= 1)
        #pragma unroll
        for (int r = 0; r < 4; r++)
            part[r] += __shfl_down(part[r], off, 16);
    if (m == 0) {
        #pragma unroll
        for (int r = 0; r < 4; r++) osum[wave][quad * 4 + r] = part[r];
    }
    __syncthreads();
    if (threadIdx.x < 16)
        out[r0 + threadIdx.x] = osum[0][threadIdx.x] + osum[1][threadIdx.x] +
                                osum[2][threadIdx.x] + osum[3][threadIdx.x] + b3[0];
}

extern "C" void kernel_launch(void* const* d_in, const int* in_sizes, int n_in,
                              void* d_out, int out_size, void* d_ws, size_t ws_size,
                              hipStream_t stream) {
    const float* state  = (const float*)d_in[0];
    const int*   edge   = (const int*)d_in[1];   // [2, E]: src row then dst row
    const float* action = (const float*)d_in[2];
    const float* W_gcn  = (const float*)d_in[3];
    const float* b_gcn  = (const float*)d_in[4];
    const float* W1     = (const float*)d_in[5];
    const float* b1     = (const float*)d_in[6];
    const float* W2     = (const float*)d_in[7];
    const float* b2     = (const float*)d_in[8];
    const float* W3     = (const float*)d_in[9];
    const float* b3     = (const float*)d_in[10];
    float* out = (float*)d_out;

    int N = in_sizes[0] / 128;
    int E = in_sizes[1] / 2;
    int B = out_size;
    const int* e_src = edge;
    const int* e_dst = edge + E;

    // workspace: xws bf16[N*128] | xB bf16[B*128] | Wgt bf16[128*128]
    //          | W1t bf16[256*128] | W2t bf16[256*256] | sstate f32[B*128]
    //          | dinv f32[N] | deg i32[N] | head i32[N] | nxt i32[E]
    __bf16* xws = (__bf16*)d_ws;
    __bf16* xB  = xws + (size_t)N * 128;
    __bf16* Wgt = xB + (size_t)B * 128;
    __bf16* W1t = Wgt + 128 * 128;
    __bf16* W2t = W1t + 256 * 128;
    float* sstate = (float*)(W2t + 256 * 256);
    float* dinv = sstate + (size_t)B * 128;
    int*   deg  = (int*)(dinv + N);
    int*   head = deg + N;
    int*   nxt  = head + N;

    hipMemsetAsync(deg, 0, (size_t)N * sizeof(int), stream);
    hipMemsetAsync(head, 0xFF, (size_t)N * sizeof(int), stream);  // -1
    hipMemsetAsync(sstate, 0, (size_t)B * 128 * sizeof(float), stream);

    k_tconv<<<(128 * 128 + 255) / 256, 256, 0, stream>>>(W_gcn, Wgt, 7, 128 * 128, 128);
    k_tconv<<<(256 * 128 + 255) / 256, 256, 0, stream>>>(W1, W1t, 7, 256 * 128, 256);
    k_tconv<<<(256 * 256 + 255) / 256, 256, 0, stream>>>(W2, W2t, 8, 256 * 256, 256);
    k_edges<<<(E + 255) / 256, 256, 0, stream>>>(e_dst, E, deg, head, nxt);
    k_dinv<<<(N + 255) / 256, 256, 0, stream>>>(deg, dinv, N);
    k_gemm<<<(N + 63) / 64, 256, 0, stream>>>(state, Wgt, dinv, action, xws,
                                              sstate, N, B);
    k_readout<<<B, 128, 0, stream>>>(head, nxt, e_src, dinv, xws, sstate, b_gcn,
                                     action, xB, B);
    k_mlp<<<B / 16, 256, 0, stream>>>(xB, W1t, b1, W2t, b2, W3, b3, out, B);
}

// Round 6
// 719.818 us; speedup vs baseline: 1.1727x; 1.1727x over previous
//
#include <hip/hip_runtime.h>

// Sizes: N=500000, C=128, H=256, A=10, E=600000, B=50000.
// R6: gemm with coalesced bf16 LDS staging for A AND LDS-transposed epilogue
// (b128 coalesced stores). Residual fusion reverted (R5's LDS atomics were a
// 2x loss); readout reads state directly as in R4.

typedef __bf16 bf16x8 __attribute__((ext_vector_type(8)));
typedef float f32x4 __attribute__((ext_vector_type(4)));

// ---- per-edge: degree count + adjacency linked list -------------------------
__global__ __launch_bounds__(256) void k_edges(const int* __restrict__ dst, int E,
                                               int* __restrict__ deg,
                                               int* __restrict__ head,
                                               int* __restrict__ nxt) {
    int e = blockIdx.x * 256 + threadIdx.x;
    if (e < E) {
        int d = dst[e];
        atomicAdd(&deg[d], 1);
        nxt[e] = atomicExch(&head[d], e);
    }
}

// ---- dinv = rsqrt(deg + 1)  (+1 = self loop) --------------------------------
__global__ __launch_bounds__(256) void k_dinv(const int* __restrict__ deg,
                                              float* __restrict__ dinv, int N) {
    int i = blockIdx.x * 256 + threadIdx.x;
    if (i < N) dinv[i] = rsqrtf((float)deg[i] + 1.0f);
}

// ---- transpose-convert weights: Wt[n*K+k] = bf16(W[k*Nc+n]) -----------------
__global__ __launch_bounds__(256) void k_tconv(const float* __restrict__ W,
                                               __bf16* __restrict__ Wt,
                                               int kbits, int total, int Nc) {
    int i = blockIdx.x * 256 + threadIdx.x;
    if (i < total) {
        int n = i >> kbits;
        int k = i & ((1 << kbits) - 1);
        Wt[i] = (__bf16)W[(long)k * Nc + n];
    }
}

// ---- xws = bf16( dinv .* (state @ W_gcn) )  via MFMA 16x16x32 bf16 ----------
// Coalesced fp32->bf16 LDS staging in; LDS-transposed b128 coalesced out.
__global__ __launch_bounds__(256) void k_gemm(const float* __restrict__ X,
                                              const __bf16* __restrict__ Wt,
                                              const float* __restrict__ dinv,
                                              __bf16* __restrict__ Y, int N) {
    __shared__ __bf16 xt[64 * 136];   // 64 rows, stride 136 (pad 8) = 17 KB
    int tid = threadIdx.x;
    long row0 = (long)blockIdx.x * 64;
    // stage 64x128 fp32 -> bf16 LDS, 32 B/lane coalesced
    #pragma unroll
    for (int it = 0; it < 4; it++) {
        int r = it * 16 + (tid >> 4);
        long row = row0 + r;
        if (row < N) {
            int c0 = (tid & 15) * 8;
            const float* p = X + row * 128 + c0;
            float4 v0 = *(const float4*)p;
            float4 v1 = *(const float4*)(p + 4);
            bf16x8 bv = {(__bf16)v0.x, (__bf16)v0.y, (__bf16)v0.z, (__bf16)v0.w,
                         (__bf16)v1.x, (__bf16)v1.y, (__bf16)v1.z, (__bf16)v1.w};
            *(bf16x8*)(xt + r * 136 + c0) = bv;
        }
    }
    __syncthreads();
    int wave = tid >> 6, lane = tid & 63;
    int m = lane & 15, quad = lane >> 4;
    long wrow0 = row0 + wave * 16;
    bool valid = wrow0 < N;     // N%16==0: valid wave tile is fully valid
    f32x4 acc[8] = {};
    if (valid) {
        #pragma unroll
        for (int kt = 0; kt < 4; kt++) {
            int k0 = kt * 32 + quad * 8;
            bf16x8 a = *(const bf16x8*)(xt + (wave * 16 + m) * 136 + k0);
            #pragma unroll
            for (int t = 0; t < 8; t++) {
                bf16x8 b = *(const bf16x8*)(Wt + (t * 16 + m) * 128 + k0);
                acc[t] = __builtin_amdgcn_mfma_f32_16x16x32_bf16(a, b, acc[t],
                                                                  0, 0, 0);
            }
        }
    }
    __syncthreads();   // done reading xt as input; reuse as output tile
    if (valid) {
        float dv[4];
        #pragma unroll
        for (int r = 0; r < 4; r++) dv[r] = dinv[wrow0 + quad * 4 + r];
        #pragma unroll
        for (int t = 0; t < 8; t++)
            #pragma unroll
            for (int r = 0; r < 4; r++)
                xt[(wave * 16 + quad * 4 + r) * 136 + t * 16 + m] =
                    (__bf16)(acc[t][r] * dv[r]);
    }
    __syncthreads();
    // coalesced b128 stores: 16 B/lane, 256 B per 16-lane group
    #pragma unroll
    for (int it = 0; it < 4; it++) {
        int r = it * 16 + (tid >> 4);
        long row = row0 + r;
        if (row < N) {
            int c0 = (tid & 15) * 8;
            *(bf16x8*)(Y + row * 128 + c0) = *(const bf16x8*)(xt + r * 136 + c0);
        }
    }
}

// ---- fused aggregate + relu + residual + action-weighted readout ------------
// One block per b. 128 thr = 8 node slots x 16 lanes; lane owns 8 channels.
__global__ __launch_bounds__(128) void k_readout(const int* __restrict__ head,
                                                 const int* __restrict__ nxt,
                                                 const int* __restrict__ e_src,
                                                 const float* __restrict__ dinv,
                                                 const __bf16* __restrict__ xws,
                                                 const float* __restrict__ state,
                                                 const float* __restrict__ bgcn,
                                                 const float* __restrict__ action,
                                                 __bf16* __restrict__ xB, int B) {
    __shared__ float red[16][8];
    int b = blockIdx.x;
    int tid = threadIdx.x;
    int lane16 = tid & 15;
    int slot = tid >> 4;       // 0..7
    int c0 = lane16 * 8;
    float4 bg0 = *(const float4*)(bgcn + c0);
    float4 bg1 = *(const float4*)(bgcn + c0 + 4);
    float bg[8] = {bg0.x, bg0.y, bg0.z, bg0.w, bg1.x, bg1.y, bg1.z, bg1.w};
    float acc[8] = {};
    for (int a = slot; a < 10; a += 8) {
        int n = b * 10 + a;
        float s[8];
        bf16x8 x = *(const bf16x8*)(xws + (size_t)n * 128 + c0);
        #pragma unroll
        for (int k = 0; k < 8; k++) s[k] = (float)x[k];
        for (int j = head[n]; j >= 0; j = nxt[j]) {
            int sr = e_src[j];
            bf16x8 g = *(const bf16x8*)(xws + (size_t)sr * 128 + c0);
            #pragma unroll
            for (int k = 0; k < 8; k++) s[k] += (float)g[k];
        }
        float di = dinv[n];
        float aw = action[n] * 10.f;
        float4 st0 = *(const float4*)(state + (size_t)n * 128 + c0);
        float4 st1 = *(const float4*)(state + (size_t)n * 128 + c0 + 4);
        float st[8] = {st0.x, st0.y, st0.z, st0.w, st1.x, st1.y, st1.z, st1.w};
        #pragma unroll
        for (int k = 0; k < 8; k++)
            acc[k] += aw * (fmaxf(di * s[k] + bg[k], 0.f) + st[k]);
    }
    #pragma unroll
    for (int k = 0; k < 8; k++) {
        acc[k] += __shfl_down(acc[k], 32);
        acc[k] += __shfl_down(acc[k], 16);
    }
    if (tid >= 64 && tid < 80) {
        #pragma unroll
        for (int k = 0; k < 8; k++) red[tid - 64][k] = acc[k];
    }
    __syncthreads();
    if (tid < 16) {
        bf16x8 o;
        #pragma unroll
        for (int k = 0; k < 8; k++) o[k] = (__bf16)(acc[k] + red[tid][k]);
        *(bf16x8*)(xB + (size_t)b * 128 + c0) = o;
    }
}

// ---- MLP head via MFMA: relu(x@W1+b1) -> relu(@W2+b2) -> @W3+b3 -------------
__global__ __launch_bounds__(256) void k_mlp(const __bf16* __restrict__ xB,
                                             const __bf16* __restrict__ W1t,
                                             const float* __restrict__ b1,
                                             const __bf16* __restrict__ W2t,
                                             const float* __restrict__ b2,
                                             const float* __restrict__ W3,
                                             const float* __restrict__ b3,
                                             float* __restrict__ out, int B) {
    __shared__ __bf16 hs[16][264];
    __shared__ float osum[4][16];
    int wave = threadIdx.x >> 6;
    int lane = threadIdx.x & 63;
    int m = lane & 15;
    int quad = lane >> 4;
    long r0 = (long)blockIdx.x * 16;

    f32x4 acc[4] = {};
    #pragma unroll
    for (int kt = 0; kt < 4; kt++) {
        int k0 = kt * 32 + quad * 8;
        bf16x8 a = *(const bf16x8*)(xB + (r0 + m) * 128 + k0);
        #pragma unroll
        for (int t = 0; t < 4; t++) {
            int n = wave * 64 + t * 16 + m;
            bf16x8 b = *(const bf16x8*)(W1t + (long)n * 128 + k0);
            acc[t] = __builtin_amdgcn_mfma_f32_16x16x32_bf16(a, b, acc[t], 0, 0, 0);
        }
    }
    #pragma unroll
    for (int t = 0; t < 4; t++) {
        int n = wave * 64 + t * 16 + m;
        float bb = b1[n];
        #pragma unroll
        for (int r = 0; r < 4; r++)
            hs[quad * 4 + r][n] = (__bf16)fmaxf(acc[t][r] + bb, 0.f);
    }
    __syncthreads();

    f32x4 acc2[4] = {};
    #pragma unroll
    for (int kt = 0; kt < 8; kt++) {
        int k0 = kt * 32 + quad * 8;
        bf16x8 a = *(const bf16x8*)(&hs[m][k0]);
        #pragma unroll
        for (int t = 0; t < 4; t++) {
            int n = wave * 64 + t * 16 + m;
            bf16x8 b = *(const bf16x8*)(W2t + (long)n * 256 + k0);
            acc2[t] = __builtin_amdgcn_mfma_f32_16x16x32_bf16(a, b, acc2[t], 0, 0, 0);
        }
    }

    float part[4] = {0.f, 0.f, 0.f, 0.f};
    #pragma unroll
    for (int t = 0; t < 4; t++) {
        int n = wave * 64 + t * 16 + m;
        float bb = b2[n], w3 = W3[n];
        #pragma unroll
        for (int r = 0; r < 4; r++)
            part[r] += fmaxf(acc2[t][r] + bb, 0.f) * w3;
    }
    #pragma unroll
    for (int off = 8; off; off >>= 1)
        #pragma unroll
        for (int r = 0; r < 4; r++)
            part[r] += __shfl_down(part[r], off, 16);
    if (m == 0) {
        #pragma unroll
        for (int r = 0; r < 4; r++) osum[wave][quad * 4 + r] = part[r];
    }
    __syncthreads();
    if (threadIdx.x < 16)
        out[r0 + threadIdx.x] = osum[0][threadIdx.x] + osum[1][threadIdx.x] +
                                osum[2][threadIdx.x] + osum[3][threadIdx.x] + b3[0];
}

extern "C" void kernel_launch(void* const* d_in, const int* in_sizes, int n_in,
                              void* d_out, int out_size, void* d_ws, size_t ws_size,
                              hipStream_t stream) {
    const float* state  = (const float*)d_in[0];
    const int*   edge   = (const int*)d_in[1];   // [2, E]: src row then dst row
    const float* action = (const float*)d_in[2];
    const float* W_gcn  = (const float*)d_in[3];
    const float* b_gcn  = (const float*)d_in[4];
    const float* W1     = (const float*)d_in[5];
    const float* b1     = (const float*)d_in[6];
    const float* W2     = (const float*)d_in[7];
    const float* b2     = (const float*)d_in[8];
    const float* W3     = (const float*)d_in[9];
    const float* b3     = (const float*)d_in[10];
    float* out = (float*)d_out;

    int N = in_sizes[0] / 128;
    int E = in_sizes[1] / 2;
    int B = out_size;
    const int* e_src = edge;
    const int* e_dst = edge + E;

    // workspace: xws bf16[N*128] | xB bf16[B*128] | Wgt bf16[128*128]
    //          | W1t bf16[256*128] | W2t bf16[256*256]
    //          | dinv f32[N] | deg i32[N] | head i32[N] | nxt i32[E]
    __bf16* xws = (__bf16*)d_ws;
    __bf16* xB  = xws + (size_t)N * 128;
    __bf16* Wgt = xB + (size_t)B * 128;
    __bf16* W1t = Wgt + 128 * 128;
    __bf16* W2t = W1t + 256 * 128;
    float* dinv = (float*)(W2t + 256 * 256);
    int*   deg  = (int*)(dinv + N);
    int*   head = deg + N;
    int*   nxt  = head + N;

    hipMemsetAsync(deg, 0, (size_t)N * sizeof(int), stream);
    hipMemsetAsync(head, 0xFF, (size_t)N * sizeof(int), stream);  // -1

    k_tconv<<<(128 * 128 + 255) / 256, 256, 0, stream>>>(W_gcn, Wgt, 7, 128 * 128, 128);
    k_tconv<<<(256 * 128 + 255) / 256, 256, 0, stream>>>(W1, W1t, 7, 256 * 128, 256);
    k_tconv<<<(256 * 256 + 255) / 256, 256, 0, stream>>>(W2, W2t, 8, 256 * 256, 256);
    k_edges<<<(E + 255) / 256, 256, 0, stream>>>(e_dst, E, deg, head, nxt);
    k_dinv<<<(N + 255) / 256, 256, 0, stream>>>(deg, dinv, N);
    k_gemm<<<(N + 63) / 64, 256, 0, stream>>>(state, Wgt, dinv, xws, N);
    k_readout<<<B, 128, 0, stream>>>(head, nxt, e_src, dinv, xws, state, b_gcn,
                                     action, xB, B);
    k_mlp<<<B / 16, 256, 0, stream>>>(xB, W1t, b1, W2t, b2, W3, b3, out, B);
}